// Round 1
// baseline (688.995 us; speedup 1.0000x reference)
//
#include <hip/hip_runtime.h>

#define TPB 256

// ---------------------------------------------------------------------------
// Semantics (derived from the JAX reference, exploiting filled == M):
//   hit  (mapping[id] != -1): slot s; evicted iff access_tick[s] < num_unique
//        -> evicted: out = cpu_table[U[access_tick[s]]]  (U = sorted unique miss ids)
//        -> else:    out = cache_data[s]
//   miss (mapping[id] == -1): out = cpu_table[id]
// General free-slot path (alloc_free > 0) handled too, though dead for this input.
// ---------------------------------------------------------------------------

__global__ void k_zero(unsigned* __restrict__ bm, int words) {
  int i = blockIdx.x * blockDim.x + threadIdx.x;
  if (i < words) bm[i] = 0u;
}

__global__ void k_mark(const int* __restrict__ flat, const int* __restrict__ mapping,
                       unsigned* __restrict__ bm, int N) {
  int i = blockIdx.x * blockDim.x + threadIdx.x;
  if (i >= N) return;
  int id = flat[i];
  if (mapping[id] == -1) {
    unsigned bit = 1u << (id & 31);
    // test-first to cut duplicate atomics
    if (!(bm[id >> 5] & bit)) atomicOr(&bm[id >> 5], bit);
  }
}

__global__ void k_blocksum(const unsigned* __restrict__ bm, int words,
                           unsigned* __restrict__ bs) {
  __shared__ unsigned s[TPB];
  int w = blockIdx.x * TPB + threadIdx.x;
  unsigned c = (w < words) ? (unsigned)__popc(bm[w]) : 0u;
  s[threadIdx.x] = c;
  __syncthreads();
  for (int off = TPB / 2; off > 0; off >>= 1) {
    if (threadIdx.x < off) s[threadIdx.x] += s[threadIdx.x + off];
    __syncthreads();
  }
  if (threadIdx.x == 0) bs[blockIdx.x] = s[0];
}

// single block, 1024 threads, scans up to 1024 block sums
__global__ void k_scanblocks(const unsigned* __restrict__ bs, int nblk,
                             unsigned* __restrict__ boff, unsigned* __restrict__ numUnique) {
  __shared__ unsigned s[1024];
  int t = threadIdx.x;
  unsigned v = (t < nblk) ? bs[t] : 0u;
  s[t] = v;
  __syncthreads();
  for (int off = 1; off < 1024; off <<= 1) {
    unsigned x = (t >= off) ? s[t - off] : 0u;
    __syncthreads();
    s[t] += x;
    __syncthreads();
  }
  if (t < nblk) boff[t] = s[t] - v;   // exclusive prefix
  if (t == 1023) *numUnique = s[1023];
}

__global__ void k_emit(const unsigned* __restrict__ bm, int words,
                       const unsigned* __restrict__ boff, int* __restrict__ U) {
  __shared__ unsigned s[TPB];
  int t = threadIdx.x;
  int w = blockIdx.x * TPB + t;
  unsigned bits = (w < words) ? bm[w] : 0u;
  unsigned c = (unsigned)__popc(bits);
  s[t] = c;
  __syncthreads();
  for (int off = 1; off < TPB; off <<= 1) {
    unsigned x = (t >= off) ? s[t - off] : 0u;
    __syncthreads();
    s[t] += x;
    __syncthreads();
  }
  unsigned pos = boff[blockIdx.x] + s[t] - c;  // exclusive within grid
  int base = w * 32;
  while (bits) {
    int b = __ffs(bits) - 1;
    U[pos++] = base + b;
    bits &= bits - 1;
  }
}

__global__ void k_resolve(const int* __restrict__ flat, const int* __restrict__ mapping,
                          const int* __restrict__ tick, const int* __restrict__ U,
                          const unsigned* __restrict__ numUniquePtr,
                          const int* __restrict__ filledPtr,
                          int* __restrict__ srcCode, int N, int M) {
  int i = blockIdx.x * blockDim.x + threadIdx.x;
  if (i >= N) return;
  int id = flat[i];
  int s = mapping[id];
  int code;
  if (s == -1) {
    code = id;                       // miss: row comes from cpu_table[id]
  } else {
    int nu = (int)*numUniquePtr;
    int filled = *filledPtr;
    int freeCap = M - filled; if (freeCap < 0) freeCap = 0;
    int allocFree = nu < freeCap ? nu : freeCap;
    int tk = tick[s];
    int k = tk + allocFree;          // eviction position of slot s, if any
    if (k < nu) code = U[k];         // slot evicted -> new id's cpu row
    else if (allocFree > 0 && s >= filled && (s - filled) < allocFree)
      code = U[s - filled];          // free-slot fill path (dead when filled==M)
    else code = ~s;                  // untouched cache slot
  }
  srcCode[i] = code;
}

// 8 rows per 256-thread block; 32 lanes x float4 covers D=128 in one step
__global__ void k_gather(const int* __restrict__ srcCode,
                         const float* __restrict__ cpu_table,
                         const float* __restrict__ cache,
                         float* __restrict__ out, int N, int D) {
  int row = blockIdx.x * 8 + (threadIdx.x >> 5);
  if (row >= N) return;
  int lane = threadIdx.x & 31;
  int code = srcCode[row];
  const float4* sp = (code >= 0)
      ? (const float4*)(cpu_table + (size_t)code * D)
      : (const float4*)(cache + (size_t)(~code) * D);
  float4* op = (float4*)(out + (size_t)row * D);
  int nv = D >> 2;
  for (int i = lane; i < nv; i += 32) op[i] = sp[i];
}

extern "C" void kernel_launch(void* const* d_in, const int* in_sizes, int n_in,
                              void* d_out, int out_size, void* d_ws, size_t ws_size,
                              hipStream_t stream) {
  const int*   indices   = (const int*)d_in[0];
  const float* cpu_table = (const float*)d_in[1];
  const float* cache     = (const float*)d_in[2];
  const int*   mapping   = (const int*)d_in[3];
  const int*   tick      = (const int*)d_in[4];
  // d_in[5] slot_to_id: not needed (only gates mapping invalidation, which
  //   cannot affect the output — hit slots were resolved before mutation)
  const int*   filled    = (const int*)d_in[6];
  float*       out       = (float*)d_out;

  int N = in_sizes[0];
  int V = in_sizes[3];
  int M = in_sizes[4];
  int D = in_sizes[1] / V;

  int words = (V + 31) >> 5;
  int nblk  = (words + TPB - 1) / TPB;   // 123 for V=1e6; k_scanblocks handles <=1024

  // workspace layout (all 4-byte aligned; ~1.73 MB total)
  unsigned* bm        = (unsigned*)d_ws;       // words
  unsigned* bs        = bm + words;            // <=1024
  unsigned* boff      = bs + 1024;             // <=1024
  unsigned* numUnique = boff + 1024;           // 1 (+3 pad)
  int*      U         = (int*)(numUnique + 4); // N
  int*      srcCode   = U + N;                 // N

  k_zero      <<<(words + TPB - 1) / TPB, TPB, 0, stream>>>(bm, words);
  k_mark      <<<(N + TPB - 1) / TPB,     TPB, 0, stream>>>(indices, mapping, bm, N);
  k_blocksum  <<<nblk,                    TPB, 0, stream>>>(bm, words, bs);
  k_scanblocks<<<1,                      1024, 0, stream>>>(bs, nblk, boff, numUnique);
  k_emit      <<<nblk,                    TPB, 0, stream>>>(bm, words, boff, U);
  k_resolve   <<<(N + TPB - 1) / TPB,     TPB, 0, stream>>>(indices, mapping, tick, U,
                                                            numUnique, filled, srcCode, N, M);
  k_gather    <<<(N + 7) / 8,             TPB, 0, stream>>>(srcCode, cpu_table, cache, out, N, D);
}

// Round 2
// 686.985 us; speedup vs baseline: 1.0029x; 1.0029x over previous
//
#include <hip/hip_runtime.h>

#define TPB 256

// ---------------------------------------------------------------------------
// Semantics (derived from the JAX reference, exploiting filled == M):
//   hit  (mapping[id] != -1): slot s; evicted iff access_tick[s] < num_unique
//        -> evicted: out = cpu_table[U[access_tick[s]]]  (U = sorted unique miss ids)
//        -> else:    out = cache_data[s]
//   miss (mapping[id] == -1): out = cpu_table[id]
// General free-slot path (alloc_free > 0) handled too, though dead for this input.
// ---------------------------------------------------------------------------

using f4 = __attribute__((ext_vector_type(4))) float;

__global__ void k_mark(const int* __restrict__ flat, const int* __restrict__ mapping,
                       unsigned* __restrict__ bm, int N) {
  int i = blockIdx.x * blockDim.x + threadIdx.x;
  if (i >= N) return;
  int id = flat[i];
  if (mapping[id] == -1) {
    unsigned bit = 1u << (id & 31);
    if (!(bm[id >> 5] & bit)) atomicOr(&bm[id >> 5], bit);  // test-first cuts dup atomics
  }
}

__global__ void k_blocksum(const unsigned* __restrict__ bm, int words,
                           unsigned* __restrict__ bs) {
  __shared__ unsigned s[TPB];
  int w = blockIdx.x * TPB + threadIdx.x;
  unsigned c = (w < words) ? (unsigned)__popc(bm[w]) : 0u;
  s[threadIdx.x] = c;
  __syncthreads();
  for (int off = TPB / 2; off > 0; off >>= 1) {
    if (threadIdx.x < off) s[threadIdx.x] += s[threadIdx.x + off];
    __syncthreads();
  }
  if (threadIdx.x == 0) bs[blockIdx.x] = s[0];
}

// single block, 1024 threads, scans up to 1024 block sums
__global__ void k_scanblocks(const unsigned* __restrict__ bs, int nblk,
                             unsigned* __restrict__ boff, unsigned* __restrict__ numUnique) {
  __shared__ unsigned s[1024];
  int t = threadIdx.x;
  unsigned v = (t < nblk) ? bs[t] : 0u;
  s[t] = v;
  __syncthreads();
  for (int off = 1; off < 1024; off <<= 1) {
    unsigned x = (t >= off) ? s[t - off] : 0u;
    __syncthreads();
    s[t] += x;
    __syncthreads();
  }
  if (t < nblk) boff[t] = s[t] - v;   // exclusive prefix
  if (t == 1023) *numUnique = s[1023];
}

__global__ void k_emit(const unsigned* __restrict__ bm, int words,
                       const unsigned* __restrict__ boff, int* __restrict__ U) {
  __shared__ unsigned s[TPB];
  int t = threadIdx.x;
  int w = blockIdx.x * TPB + t;
  unsigned bits = (w < words) ? bm[w] : 0u;
  unsigned c = (unsigned)__popc(bits);
  s[t] = c;
  __syncthreads();
  for (int off = 1; off < TPB; off <<= 1) {
    unsigned x = (t >= off) ? s[t - off] : 0u;
    __syncthreads();
    s[t] += x;
    __syncthreads();
  }
  unsigned pos = boff[blockIdx.x] + s[t] - c;  // exclusive within grid
  int base = w * 32;
  while (bits) {
    int b = __ffs(bits) - 1;
    U[pos++] = base + b;
    bits &= bits - 1;
  }
}

// Fused resolve + gather: 8 rows per 256-thread block, 32 lanes/row.
// Lane 0 of each 32-group resolves the row source via the small cached
// tables (flat -> mapping -> tick -> U), broadcasts; then all 32 lanes
// stream the 512B row with nontemporal f4 ops (no reuse of this data).
__global__ void k_out(const int* __restrict__ flat, const int* __restrict__ mapping,
                      const int* __restrict__ tick, const int* __restrict__ U,
                      const unsigned* __restrict__ nuPtr, const int* __restrict__ filledPtr,
                      const float* __restrict__ cpu, const float* __restrict__ cache,
                      float* __restrict__ out, int N, int M, int D) {
  int row = blockIdx.x * 8 + (threadIdx.x >> 5);
  if (row >= N) return;
  int lane = threadIdx.x & 31;
  int code = 0;
  if (lane == 0) {
    int id = flat[row];
    int s = mapping[id];
    if (s == -1) {
      code = id;                         // miss: cpu_table[id]
    } else {
      int nu = (int)*nuPtr;
      int filled = *filledPtr;
      int freeCap = M - filled; if (freeCap < 0) freeCap = 0;
      int allocFree = nu < freeCap ? nu : freeCap;
      int k = tick[s] + allocFree;       // eviction position of slot s, if any
      if (k < nu) code = U[k];           // evicted -> new occupant's cpu row
      else if (allocFree > 0 && s >= filled && (s - filled) < allocFree)
        code = U[s - filled];            // free-slot fill (dead when filled==M)
      else code = ~s;                    // untouched cache slot
    }
  }
  code = __shfl(code, 0, 32);
  const f4* sp = (code >= 0)
      ? (const f4*)(cpu + (size_t)code * D)
      : (const f4*)(cache + (size_t)(~code) * D);
  f4* op = (f4*)(out + (size_t)row * D);
  int nv = D >> 2;
  for (int i = lane; i < nv; i += 32) {
    f4 v = __builtin_nontemporal_load(&sp[i]);
    __builtin_nontemporal_store(v, &op[i]);
  }
}

extern "C" void kernel_launch(void* const* d_in, const int* in_sizes, int n_in,
                              void* d_out, int out_size, void* d_ws, size_t ws_size,
                              hipStream_t stream) {
  const int*   indices   = (const int*)d_in[0];
  const float* cpu_table = (const float*)d_in[1];
  const float* cache     = (const float*)d_in[2];
  const int*   mapping   = (const int*)d_in[3];
  const int*   tick      = (const int*)d_in[4];
  // d_in[5] slot_to_id: not needed (gates only mapping invalidation, which
  //   cannot affect the output)
  const int*   filled    = (const int*)d_in[6];
  float*       out       = (float*)d_out;

  int N = in_sizes[0];
  int V = in_sizes[3];
  int M = in_sizes[4];
  int D = in_sizes[1] / V;

  int words = (V + 31) >> 5;
  int nblk  = (words + TPB - 1) / TPB;   // 123 for V=1e6; k_scanblocks handles <=1024

  // workspace layout (all 4-byte aligned; ~1 MB total)
  unsigned* bm        = (unsigned*)d_ws;       // words
  unsigned* bs        = bm + words;            // <=1024
  unsigned* boff      = bs + 1024;             // <=1024
  unsigned* numUnique = boff + 1024;           // 1 (+3 pad)
  int*      U         = (int*)(numUnique + 4); // N

  hipMemsetAsync(bm, 0, (size_t)words * 4, stream);
  k_mark      <<<(N + TPB - 1) / TPB, TPB, 0, stream>>>(indices, mapping, bm, N);
  k_blocksum  <<<nblk,                TPB, 0, stream>>>(bm, words, bs);
  k_scanblocks<<<1,                  1024, 0, stream>>>(bs, nblk, boff, numUnique);
  k_emit      <<<nblk,                TPB, 0, stream>>>(bm, words, boff, U);
  k_out       <<<(N + 7) / 8,         TPB, 0, stream>>>(indices, mapping, tick, U,
                                                        numUnique, filled,
                                                        cpu_table, cache, out, N, M, D);
}